// Round 11
// baseline (138.650 us; speedup 1.0000x reference)
//
#include <hip/hip_runtime.h>
#include <hip/hip_bf16.h>
#include <stdint.h>

typedef __attribute__((ext_vector_type(8))) short short8;
typedef __attribute__((ext_vector_type(4))) float f32x4;

// ---------------- ws layout (bytes) ----------------
// Xpad granules: [b(8)][cb(8)][y(66)][x(66)][slot(4)] * 16B = 17,842,176
//   slot = sub ^ ((xp>>1)&3)  (bank key x&7 -> conflict-free b128 reads)
#define XP_BYTES   17842176
#define XP_PAD     1024
#define OFF_W9     (XP_BYTES + XP_PAD)            // 17,843,200
#define W9_BYTES   (8*9*256*32*2)                 // 1,179,648
#define OFF_BIAS   (OFF_W9 + W9_BYTES)

__device__ __forceinline__ short f2bf(float f) {
  __hip_bfloat16 h = __float2bfloat16(f);
  return *reinterpret_cast<short*>(&h);
}

__device__ __forceinline__ void gl_lds16(const void* g, void* l) {
  __builtin_amdgcn_global_load_lds(
      (const __attribute__((address_space(1))) void*)g,
      (__attribute__((address_space(3))) void*)l, 16, 0, 0);
}

// Fused prep (r10 version). Blocks [0,512): pad+transpose fat blocks
// (one per (b,cb,row-octant)); blocks [512,768): weight prep, one per o.
__global__ void k_prep(const float* __restrict__ X,
                       const float* __restrict__ core1,
                       const float* __restrict__ core2,
                       const float* __restrict__ core3,
                       const float* __restrict__ convw,
                       const float* __restrict__ convb,
                       short* __restrict__ Xp,
                       short* __restrict__ W9, float* __restrict__ bias) {
  if (blockIdx.x < 512) {
    // ---------------- pad+transpose ----------------
    const int p = blockIdx.x;
    const int bc = p >> 3, g = p & 7;
    const int b = bc >> 3, cb = bc & 7;
    const int y0 = (g < 2) ? g * 9 : 18 + (g - 2) * 8;   // rows [y0, y0+ny)
    const int ny = (g < 2) ? 9 : 8;                      // 9+9+8*6 = 66
    const int t = threadIdx.x;
    const short8 z = (short8){0, 0, 0, 0, 0, 0, 0, 0};
    __shared__ __align__(16) short Ls[264 * 8];   // one padded row, 4224 B
    if (t < 8) {
      const int gid = (t < 4) ? t : 260 + (t - 4);
      *(short8*)&Ls[gid * 8] = z;
    }
    const int x = t & 63, sub = t >> 6, xp = x + 1;
    const int gslot = sub ^ ((xp >> 1) & 3);
    for (int r = 0; r < ny; ++r) {
      const int yp = y0 + r;
      short* rowp = Xp + ((size_t)((b * 8 + cb) * 66 + yp)) * 264 * 8;
      if (yp == 0 || yp == 65) {
        *(short8*)(rowp + t * 8) = z;
        if (t < 8) *(short8*)(rowp + (256 + t) * 8) = z;
        continue;
      }
      const int y = yp - 1;
      const float* src =
          X + ((size_t)(b * 256 + cb * 32 + sub * 8) * 64 + y) * 64 + x;
      short8 v;
#pragma unroll
      for (int k = 0; k < 8; ++k) v[k] = f2bf(src[(size_t)k * 4096]);
      __syncthreads();                  // prev row's write-out done
      *(short8*)&Ls[(xp * 4 + gslot) * 8] = v;
      __syncthreads();
      *(short8*)(rowp + t * 8) = *(const short8*)&Ls[t * 8];
      if (t < 8)
        *(short8*)(rowp + (256 + t) * 8) = *(const short8*)&Ls[(256 + t) * 8];
    }
    return;
  }
  // ---------------- weights ----------------
  __shared__ float H2s[1024];   // [u(16)][j(8)][k(8)]
  __shared__ float red[256];
  const int o = blockIdx.x - 512, c = threadIdx.x;
  const int a = o >> 6, c2 = (o >> 3) & 7, d = o & 7;
#pragma unroll
  for (int p = 0; p < 4; ++p) {
    int idx = c + (p << 8);
    int k = idx & 7, j = (idx >> 3) & 7, u = idx >> 6;
    float s = 0.f;
#pragma unroll
    for (int v = 0; v < 16; ++v)
      s += core2[(c2 * 16 + v) * 128 + u * 8 + j] * core3[d * 128 + v * 8 + k];
    H2s[idx] = s;
  }
  __syncthreads();
  const int i = c >> 6, j = (c >> 3) & 7, k = c & 7;
  float Wr[16];
#pragma unroll
  for (int r = 0; r < 16; ++r) Wr[r] = 0.f;
  for (int u = 0; u < 16; ++u) {
    float h = H2s[u * 64 + j * 8 + k];
    const float* c1 = core1 + (a * 16 + u) * 64 + i;
#pragma unroll
    for (int r = 0; r < 16; ++r) Wr[r] += c1[r * 4] * h;
  }
  // W9 layout: [cb][t][o(256)][slot(4)][8], slot = g ^ (o&3)
  const int cb = c >> 5, cl = c & 31, gg = cl >> 3, pos = cl & 7;
  const int gslot = gg ^ (o & 3);
#pragma unroll
  for (int t = 0; t < 9; ++t) {
    float s = 0.f;
#pragma unroll
    for (int r = 0; r < 16; ++r) s += Wr[r] * convw[r * 9 + t];
    W9[((size_t)((cb * 9 + t) * 256 + o)) * 32 + gslot * 8 + pos] = f2bf(s);
  }
  float s = 0.f;
#pragma unroll
  for (int r = 0; r < 16; ++r) s += Wr[r] * convb[r];
  red[c] = s;
  __syncthreads();
  for (int st = 128; st > 0; st >>= 1) {
    if (c < st) red[c] += red[c + st];
    __syncthreads();
  }
  if (c == 0) bias[o] = red[0];
}

// main GEMM, TLP round: same wave microstructure as r10 (2 rows x 32 o,
// 1/3 ds_read per MFMA, reg-dbuf bfr + setprio clusters) but 32 outputs per
// thread instead of 64 -> 8192 waves total = 16 waves/CU = 4/SIMD (every
// prior design was grid-capped at 8 waves/CU; r8 measured ~50% all-pipes-idle
// = latency-bound at 2 waves/SIMD).
// Block = 512 thr, 8 waves = 4 h-pairs x 2 x-halves; covers 8 rows x 32 o x
// 64 x. X tile 10 full-width rows = 43,008 B SINGLE buffer -> 2 blocks/CU.
// Cadence: sync; stage(cb); sync; compute (stage drain covered cross-block;
// compute phase has no in-flight stage, so af remat waits are harmless).
__global__ __launch_bounds__(512, 2) void k_gemm(
    const short* __restrict__ Xp, const short* __restrict__ W9,
    const float* __restrict__ bias, float* __restrict__ out) {
  __shared__ __align__(16) short XL[21504];   // 42 chunks = 43,008 B

  const int tid  = threadIdx.x;
  const int lane = tid & 63;
  const int wv   = tid >> 6;           // 8 waves
  const int l15  = lane & 15;
  const int gl   = lane >> 4;          // k-granule 0..3
  const int hp   = wv >> 1;            // h-pair 0..3
  const int xh   = wv & 1;             // x-half 0..1
  const int x0w  = xh << 5;            // wave x base
  const int h0    = blockIdx.x << 3;   // 8 output rows / block
  const int oBase = blockIdx.y << 5;   // 32 out-channels / block
  const int b     = blockIdx.z;
  const int r0    = hp << 1;           // wave's local output-row base (0..6)

  // LDS short-offsets: xoff[xr][dx] for padded row r0+xr, col x0w+l15+dx
  // (+512 shorts for ip=1; swizzle key (x>>1)&3 invariant under +16 and +32)
  int xoff[4][3];
#pragma unroll
  for (int xr = 0; xr < 4; ++xr)
#pragma unroll
    for (int dx = 0; dx < 3; ++dx) {
      const int x = x0w + l15 + dx;
      xoff[xr][dx] = ((r0 + xr) * 66 + x) * 32 + ((gl ^ ((x >> 1) & 3)) << 3);
    }

  // af lane offset (shorts) into W9: per (cb,t,io) add cb*73728+t*8192+io*512
  const int laneW = (oBase + l15) * 32 + ((gl ^ (l15 & 3)) << 3);

  f32x4 acc[2][2][2];   // [rr][io][ip]
#pragma unroll
  for (int rr = 0; rr < 2; ++rr)
#pragma unroll
    for (int io = 0; io < 2; ++io)
#pragma unroll
      for (int ip = 0; ip < 2; ++ip)
        acc[rr][io][ip] = (f32x4){0.f, 0.f, 0.f, 0.f};

  // stage: 10 rows x 264 granules = 2640 granules -> 42 chunks of 1KB
  // (last chunk over-reads 48 granules into the next slab / XP_PAD: benign)
#define STAGE(CB)                                                          \
  {                                                                        \
    const size_t xb = ((size_t)(((b << 3) + (CB)) * 66 + h0) * 66) << 5;   \
    _Pragma("unroll 1")                                                    \
    for (int q = wv; q < 42; q += 8)                                       \
      gl_lds16(Xp + xb + (q << 9) + (lane << 3), &XL[q << 9]);             \
  }

  for (int cb = 0; cb < 8; ++cb) {
    // af preload: 18 global b128 (L1-hot W9 slice), issued before the barrier
    const short* Wc = W9 + cb * 73728 + laneW;
    short8 af[9][2];
#pragma unroll
    for (int t = 0; t < 9; ++t)
#pragma unroll
      for (int io = 0; io < 2; ++io)
        af[t][io] = *(const short8*)&Wc[t * 8192 + (io << 9)];
    __builtin_amdgcn_sched_barrier(0);

    __syncthreads();   // all waves done reading XL (cb-1)
    STAGE(cb);
    __builtin_amdgcn_sched_barrier(0);
    __syncthreads();   // XL ready (drains stage + af)

    short8 bfr[2][4];  // [regbuf][xr], static-indexed

#define LOADS(BUF, DX, IP)                                                 \
  {                                                                        \
    _Pragma("unroll")                                                      \
    for (int xr = 0; xr < 4; ++xr)                                         \
      bfr[BUF][xr] = *(const short8*)&XL[xoff[xr][DX] + ((IP) << 9)];      \
  }

    LOADS(0, 0, 0);    // step-0 fragments
#pragma unroll
    for (int s = 0; s < 6; ++s) {
      const int dx = s >> 1, ip = s & 1, buf = s & 1;
      if (s < 5) LOADS(buf ^ 1, (s + 1) >> 1, (s + 1) & 1);
      __builtin_amdgcn_sched_barrier(0);   // reads issued before MFMA cluster
      __builtin_amdgcn_s_setprio(1);
#pragma unroll
      for (int dy = 0; dy < 3; ++dy) {
        const int t = dy * 3 + dx;
#pragma unroll
        for (int io = 0; io < 2; ++io) {
          acc[0][io][ip] = __builtin_amdgcn_mfma_f32_16x16x32_bf16(
              af[t][io], bfr[buf][dy], acc[0][io][ip], 0, 0, 0);
          acc[1][io][ip] = __builtin_amdgcn_mfma_f32_16x16x32_bf16(
              af[t][io], bfr[buf][dy + 1], acc[1][io][ip], 0, 0, 0);
        }
      }
      __builtin_amdgcn_s_setprio(0);
    }
#undef LOADS
  }
#undef STAGE

  // epilogue: rows h0+r0+rr, cols x0w + ip*16 + l15
#pragma unroll
  for (int rr = 0; rr < 2; ++rr) {
    const int h = h0 + r0 + rr;
#pragma unroll
    for (int io = 0; io < 2; ++io) {
#pragma unroll
      for (int r = 0; r < 4; ++r) {
        const int oG = oBase + (io << 4) + (gl << 2) + r;
        const float bv = bias[oG];
        float* op = out + (((size_t)((b << 8) + oG)) << 12) + (h << 6) + x0w;
#pragma unroll
        for (int ip = 0; ip < 2; ++ip)
          op[(ip << 4) + l15] = acc[rr][io][ip][r] + bv;
      }
    }
  }
}

extern "C" void kernel_launch(void* const* d_in, const int* in_sizes, int n_in,
                              void* d_out, int out_size, void* d_ws, size_t ws_size,
                              hipStream_t stream) {
  (void)in_sizes; (void)n_in; (void)out_size; (void)ws_size;
  const float* X     = (const float*)d_in[0];
  const float* convw = (const float*)d_in[1];
  const float* convb = (const float*)d_in[2];
  const float* core1 = (const float*)d_in[3];
  const float* core2 = (const float*)d_in[4];
  const float* core3 = (const float*)d_in[5];
  float* out = (float*)d_out;
  char*  ws  = (char*)d_ws;

  short* Xp   = (short*)ws;
  short* W9   = (short*)(ws + OFF_W9);
  float* bias = (float*)(ws + OFF_BIAS);

  // fused pad(512 fat blocks)+weights(256) ; no memset (pad writes all)
  k_prep<<<768, 256, 0, stream>>>(X, core1, core2, core3, convw, convb,
                                  Xp, W9, bias);
  k_gemm<<<dim3(8, 8, 8), 512, 0, stream>>>(Xp, W9, bias, out);
}